// Round 4
// baseline (221.546 us; speedup 1.0000x reference)
//
#include <hip/hip_runtime.h>
#include <math.h>

// Each float4 holds two consecutive 2-d states: (x0,y0,x1,y1).
// out = (C*x + S*y, -S*x + C*y) where [C,S] is the exact composite of the
// 1000 float32-rounded rotation steps, computed in double on the host.
__global__ __launch_bounds__(256) void lin2d_rot_kernel(
    const float4* __restrict__ in, float4* __restrict__ out,
    int n4, float C, float S) {
    int i = blockIdx.x * blockDim.x + threadIdx.x;
    if (i < n4) {
        float4 v = in[i];
        float4 r;
        r.x =  C * v.x + S * v.y;
        r.y = -S * v.x + C * v.y;
        r.z =  C * v.z + S * v.w;
        r.w = -S * v.z + C * v.w;
        out[i] = r;
    }
}

extern "C" void kernel_launch(void* const* d_in, const int* in_sizes, int n_in,
                              void* d_out, int out_size, void* d_ws, size_t ws_size,
                              hipStream_t stream) {
    (void)d_ws; (void)ws_size; (void)n_in;

    // Reproduce the float32-rounded per-step constants, then compose exactly
    // in double: M = [[c,s],[-s,c]] acting on column (x0,x1) per step.
    // M^1000 = r^1000 * [[cos(1000*phi), sin(1000*phi)], [-sin, cos]].
    const double theta = M_PI / 100.0;
    const float cf = (float)cos(theta);
    const float sf = (float)sin(theta);
    const double r   = sqrt((double)cf * cf + (double)sf * sf);
    const double phi = atan2((double)sf, (double)cf);
    const double scale = pow(r, 1000.0);
    const double ang   = 1000.0 * phi;
    const float C = (float)(scale * cos(ang));
    const float S = (float)(scale * sin(ang));

    const float4* in  = (const float4*)d_in[0];
    float4*       out = (float4*)d_out;
    const int n_elems = in_sizes[0];      // 16777216 * 2 floats
    const int n4 = n_elems / 4;           // two states per float4

    const int block = 256;
    const int grid = (n4 + block - 1) / block;
    lin2d_rot_kernel<<<grid, block, 0, stream>>>(in, out, n4, C, S);
}

// Round 6
// 215.893 us; speedup vs baseline: 1.0262x; 1.0262x over previous
//
#include <hip/hip_runtime.h>
#include <math.h>

// Each 16-byte vector holds two consecutive 2-d states: (x0,y0,x1,y1).
// out = (C*x + S*y, -S*x + C*y) where [C,S] is the exact composite of the
// 1000 float32-rounded rotation steps, computed in double on the host.
//
// NOTE: HIP's float4 is HIP_vector_type<float,4> (a class) and is NOT a
// valid operand for __builtin_nontemporal_load/store. Use a raw clang
// ext_vector_type(4) typedef instead — same 16-byte layout/alignment.
//
// Both streams are touched exactly once -> non-temporal load/store ('nt'
// flag on global_load/store_dwordx4) bypasses L2 allocation, so the 128 MB
// write stream's write-allocate lines don't evict the read stream from the
// 4 MiB-per-XCD L2s.
typedef float f32x4 __attribute__((ext_vector_type(4)));

__global__ __launch_bounds__(256) void lin2d_rot_kernel(
    const f32x4* __restrict__ in, f32x4* __restrict__ out,
    int n4, float C, float S) {
    int i = blockIdx.x * blockDim.x + threadIdx.x;
    if (i < n4) {
        f32x4 v = __builtin_nontemporal_load(in + i);
        f32x4 r;
        // Expression forms identical to the passing kernel so fp-contraction
        // (and thus absmax) is unchanged.
        r.x =  C * v.x + S * v.y;
        r.y = -S * v.x + C * v.y;
        r.z =  C * v.z + S * v.w;
        r.w = -S * v.z + C * v.w;
        __builtin_nontemporal_store(r, out + i);
    }
}

extern "C" void kernel_launch(void* const* d_in, const int* in_sizes, int n_in,
                              void* d_out, int out_size, void* d_ws, size_t ws_size,
                              hipStream_t stream) {
    (void)d_ws; (void)ws_size; (void)n_in; (void)out_size;

    // Reproduce the float32-rounded per-step constants, then compose exactly
    // in double: M = [[c,s],[-s,c]] acting on column (x0,x1) per step.
    // M^1000 = r^1000 * [[cos(1000*phi), sin(1000*phi)], [-sin, cos]].
    const double theta = M_PI / 100.0;
    const float cf = (float)cos(theta);
    const float sf = (float)sin(theta);
    const double r   = sqrt((double)cf * cf + (double)sf * sf);
    const double phi = atan2((double)sf, (double)cf);
    const double scale = pow(r, 1000.0);
    const double ang   = 1000.0 * phi;
    const float C = (float)(scale * cos(ang));
    const float S = (float)(scale * sin(ang));

    const f32x4* in  = (const f32x4*)d_in[0];
    f32x4*       out = (f32x4*)d_out;
    const int n_elems = in_sizes[0];      // 16777216 * 2 floats
    const int n4 = n_elems / 4;           // two states per 16B vector

    const int block = 256;
    const int grid = (n4 + block - 1) / block;
    lin2d_rot_kernel<<<grid, block, 0, stream>>>(in, out, n4, C, S);
}